// Round 8
// baseline (243.627 us; speedup 1.0000x reference)
//
#include <hip/hip_runtime.h>
#include <hip/hip_bf16.h>

// out[b] = ||xd_b||^2 - (s_b . xd_b)^2 / (1 + ||s_b||^2), s = x @ W^T.
// bf16 MFMA GEMM, 256x256 tile, BK=64, fused reduction epilogue.
// R8: eliminate the x-cast pass (was ~33 us, 226 MB at BW floor) by fusing
// f32->bf16 into the GEMM's A-staging: reg-stage A (global f32x4 loads ->
// v_cvt_pk_bf16_f32 -> swizzled ds_write_b128), B stays on global_load_lds.
// A-loads issued one phase ahead (P0 -> written P1, P1 -> written P2);
// compiler auto-waitcnt provides the counted vmcnt at first use, which also
// publishes the older B DMA ops (ledger in comments). Single 16-VGPR av
// buffer (issue-after-consume) keeps arch VGPR < 128 (2 waves/SIMD).
// Only W is pre-cast (25 MB, ~4 us). Epilogue moved before the final drain.

#define MTOT 16384
#define DTOT 2048
#define NTILES 32   // DTOT / 64

typedef unsigned short u16;
typedef __attribute__((ext_vector_type(4))) float f32x4;
typedef __attribute__((ext_vector_type(8))) short bf16x8;
typedef __attribute__((ext_vector_type(8))) unsigned short u16x8;

__device__ __forceinline__ u16 f2bf(float f) {
    union { float f; unsigned int u; } v; v.f = f;
    unsigned int u = v.u;
    u += 0x7fffu + ((u >> 16) & 1u);   // RNE (inputs finite)
    return (u16)(u >> 16);
}

__device__ __forceinline__ unsigned cvtpk(float lo, float hi) {
    unsigned r;
    asm("v_cvt_pk_bf16_f32 %0, %1, %2" : "=v"(r) : "v"(lo), "v"(hi));
    return r;   // bits[15:0]=bf16(lo), [31:16]=bf16(hi), RNE
}

__device__ __forceinline__ void gload_lds16(const void* gptr, void* ldsptr) {
    __builtin_amdgcn_global_load_lds(
        (const __attribute__((address_space(1))) unsigned int*)gptr,
        (__attribute__((address_space(3))) unsigned int*)ldsptr,
        16, 0, 0);
}

#define BARS()   __builtin_amdgcn_s_barrier()
#define SCHED0() __builtin_amdgcn_sched_barrier(0)
#define LGKM0()  asm volatile("s_waitcnt lgkmcnt(0)")
#define WAITV(n) asm volatile("s_waitcnt vmcnt(" #n ")")

// ---------------- cast f32 -> bf16 (W only now) ----------------
__global__ void cast_kernel(const float* __restrict__ src, u16* __restrict__ dst, int n8) {
    int stride = gridDim.x * blockDim.x;
    for (int i = blockIdx.x * blockDim.x + threadIdx.x; i < n8; i += stride) {
        f32x4 a = ((const f32x4*)src)[2 * (size_t)i];
        f32x4 b = ((const f32x4*)src)[2 * (size_t)i + 1];
        u16x8 r;
        r[0] = f2bf(a[0]); r[1] = f2bf(a[1]); r[2] = f2bf(a[2]); r[3] = f2bf(a[3]);
        r[4] = f2bf(b[0]); r[5] = f2bf(b[1]); r[6] = f2bf(b[2]); r[7] = f2bf(b[3]);
        ((u16x8*)dst)[i] = r;
    }
}

// ---------------- 256^2 GEMM, fused cast-in-staging + reductions ----------------
// grid = 512 blocks x 512 threads (8 waves, 2M x 4N). acc[8][4] per wave.
// LDS 128 KiB: [2 buf][A0,A1,B0,B1 x 16 KiB]. XCD k (= bid%8) owns W col
// panel k*256 (1 MB, L2-resident).
// Phases per tile t (R5 ks-split): P0 ks0 m0-3 | P1 ks0 m4-7 | P2 ks1 m0-3
// | P3 ks1 m4-7; 16 independent MFMA each; frag reads 8/4/8/4 b128.
// A staging (reg path): P0 issue f32 loads (t+1).A0; P1 write A0, issue A1;
// P2 write A1. B staging (DMA): P3 stages (t+2).B0+B1 into bufc.B (freed
// after P2's last B reads + P2-end barrier).
// vmcnt ledger (auto-waitcnt): at P1's A0-consume, outstanding =
// stB(t+1)[4, issued P3(t-1)] + A0[4] + (nothing newer) -> vmcnt(4)-ish wait
// drains stB(t+1) too => bufn.B published well before t+1. At P2's
// A1-consume -> drains rest. A ds_writes drained by each wave's own LGKM0
// before its P3-end barrier => bufn.A published for t+1's P0 reads.
__global__ __launch_bounds__(512, 2)
void gemm8(const float* __restrict__ xf, const u16* __restrict__ wbf,
           const float* __restrict__ xdot,
           float* __restrict__ ns_acc, float* __restrict__ sx_acc,
           float* __restrict__ xx_acc) {
    __shared__ u16 lds[65536];   // 128 KiB

    const int tid  = threadIdx.x;
    const int lane = tid & 63;
    const int wid  = tid >> 6;
    const int wr = wid >> 2, wc = wid & 3;     // 2 x 4 wave grid
    const int fr = lane & 15, fq = lane >> 4;

    const int bid  = blockIdx.x;               // 512
    const int brow = (bid >> 3) * 256;
    const int bcol = (bid & 7) * 256;

    // ---- B staging (DMA): thread covers row i>>3, 16B slot i&7, i = tid, 512+tid.
    // Swizzle via pre-swizzled global source; LDS dest linear.
    const int i0 = tid, i1 = 512 + tid;
    const int r0 = i0 >> 3, sl0 = i0 & 7;
    const int r1 = i1 >> 3, sl1 = i1 & 7;
    const size_t poff0 = (size_t)r0 * DTOT + ((sl0 ^ (r0 & 7)) << 3);
    const size_t poff1 = (size_t)r1 * DTOT + ((sl1 ^ (r1 & 7)) << 3);
    auto stB = [&](int v, int half, int ldsbyte) {      // B half-tile, K-step v
        v = v > NTILES - 1 ? NTILES - 1 : v;            // tail: idempotent restage
        const u16* base = wbf + (size_t)(bcol + half * 128) * DTOT + v * 64;
        gload_lds16(base + poff0, (char*)lds + ldsbyte + i0 * 16);
        gload_lds16(base + poff1, (char*)lds + ldsbyte + i1 * 16);
    };

    // ---- A staging (reg path, fused f32->bf16): thread covers row ar = tid>>2
    // of the 128-row half-tile, chunk ac = tid&3 (16 f32 = 64 B). Output 32 B
    // bf16 = slots 2ac, 2ac+1, swizzled ^(ar&7) at the ds_write.
    const int ar = tid >> 2, ac = tid & 3;
    const float* xbase = xf + (size_t)(brow + ar) * DTOT + ac * 16;
    f32x4 av[4];
    auto aLoad = [&](int v, int half) {
        v = v > NTILES - 1 ? NTILES - 1 : v;
        const f32x4* p = (const f32x4*)(xbase + (size_t)half * 128 * DTOT + v * 64);
#pragma unroll
        for (int q = 0; q < 4; ++q) av[q] = p[q];
    };
    auto aWrite = [&](int half, int bufbyte) {
        uint4 lo, hi;
        lo.x = cvtpk(av[0][0], av[0][1]); lo.y = cvtpk(av[0][2], av[0][3]);
        lo.z = cvtpk(av[1][0], av[1][1]); lo.w = cvtpk(av[1][2], av[1][3]);
        hi.x = cvtpk(av[2][0], av[2][1]); hi.y = cvtpk(av[2][2], av[2][3]);
        hi.z = cvtpk(av[3][0], av[3][1]); hi.w = cvtpk(av[3][2], av[3][3]);
        char* base = (char*)lds + bufbyte + half * 16384 + ar * 128;
        *(uint4*)(base + (((2 * ac) ^ (ar & 7)) << 4))     = lo;
        *(uint4*)(base + (((2 * ac + 1) ^ (ar & 7)) << 4)) = hi;
    };

    // swizzled fragment read: logical slot s -> physical s^(row&7)
#define FRAG(base_u16, row, s) \
    (*(const bf16x8*)&lds[(base_u16) + (row) * 64 + (((s) ^ ((row) & 7)) << 3)])

    f32x4 acc[8][4] = {};
    bf16x8 Af[4], Ag[4], Bf[4];

    // ---- prologue: B of tile 0 + tile 1 (DMA); A of tile 0 via reg path
    stB(0, 0, 32768);         stB(0, 1, 49152);
    stB(1, 0, 65536 + 32768); stB(1, 1, 65536 + 49152);
    aLoad(0, 0);  aWrite(0, 0);        // auto vmcnt drains B0/B1 DMA + these loads
    aLoad(0, 1);  aWrite(1, 0);
    LGKM0();      // own ds_writes drained before barrier
    BARS();       // buf0 published (each wave drained B-DMA via its av waits)

    for (int t = 0; t < NTILES; ++t) {
        const int cur   = t & 1;
        const int abase = cur * 32768 + wr * 8192;                 // u16 units
        const int bbase = cur * 32768 + 16384 + (wc >> 1) * 8192;
        const int brB   = (wc & 1) * 64;
        const int bufnB = (cur ^ 1) * 65536;   // buf of tile t+1 (bytes)
        const int bufcB = cur * 65536;         // current buf (B freed at P2)

        // ---- P0: frag ks0 A[m0-3]+B[n0-3]; issue (t+1).A0 f32; MFMA 16
#pragma unroll
        for (int m = 0; m < 4; ++m) Af[m] = FRAG(abase, m * 16 + fr, fq);
#pragma unroll
        for (int n = 0; n < 4; ++n) Bf[n] = FRAG(bbase, brB + n * 16 + fr, fq);
        aLoad(t + 1, 0);
        SCHED0(); BARS(); LGKM0();
        __builtin_amdgcn_s_setprio(1);
#pragma unroll
        for (int m = 0; m < 4; ++m)
#pragma unroll
            for (int n = 0; n < 4; ++n)
                acc[m][n] = __builtin_amdgcn_mfma_f32_16x16x32_bf16(Af[m], Bf[n], acc[m][n], 0, 0, 0);
        __builtin_amdgcn_s_setprio(0);
        SCHED0(); BARS();

        // ---- P1: frag ks0 A[m4-7]; write (t+1).A0; issue (t+1).A1; MFMA 16
#pragma unroll
        for (int m = 0; m < 4; ++m) Ag[m] = FRAG(abase, 64 + m * 16 + fr, fq);
        aWrite(0, bufnB);          // auto vmcnt: drains stB(t+1) + A0 loads
        aLoad(t + 1, 1);
        SCHED0(); BARS(); LGKM0();
        __builtin_amdgcn_s_setprio(1);
#pragma unroll
        for (int m = 0; m < 4; ++m)
#pragma unroll
            for (int n = 0; n < 4; ++n)
                acc[4 + m][n] = __builtin_amdgcn_mfma_f32_16x16x32_bf16(Ag[m], Bf[n], acc[4 + m][n], 0, 0, 0);
        __builtin_amdgcn_s_setprio(0);
        SCHED0(); BARS();

        // ---- P2: frag ks1 A[m0-3]+B[n0-3] (last B reads); write (t+1).A1; MFMA 16
#pragma unroll
        for (int m = 0; m < 4; ++m) Af[m] = FRAG(abase, m * 16 + fr, 4 + fq);
#pragma unroll
        for (int n = 0; n < 4; ++n) Bf[n] = FRAG(bbase, brB + n * 16 + fr, 4 + fq);
        aWrite(1, bufnB);
        SCHED0(); BARS(); LGKM0();
        __builtin_amdgcn_s_setprio(1);
#pragma unroll
        for (int m = 0; m < 4; ++m)
#pragma unroll
            for (int n = 0; n < 4; ++n)
                acc[m][n] = __builtin_amdgcn_mfma_f32_16x16x32_bf16(Af[m], Bf[n], acc[m][n], 0, 0, 0);
        __builtin_amdgcn_s_setprio(0);
        SCHED0(); BARS();

        // ---- P3: frag ks1 A[m4-7]; stage (t+2).B into freed bufc.B; MFMA 16
#pragma unroll
        for (int m = 0; m < 4; ++m) Ag[m] = FRAG(abase, 64 + m * 16 + fr, 4 + fq);
        stB(t + 2, 0, bufcB + 32768);
        stB(t + 2, 1, bufcB + 49152);
        SCHED0(); BARS(); LGKM0();
        __builtin_amdgcn_s_setprio(1);
#pragma unroll
        for (int m = 0; m < 4; ++m)
#pragma unroll
            for (int n = 0; n < 4; ++n)
                acc[4 + m][n] = __builtin_amdgcn_mfma_f32_16x16x32_bf16(Ag[m], Bf[n], acc[4 + m][n], 0, 0, 0);
        __builtin_amdgcn_s_setprio(0);
        SCHED0(); BARS();
    }

    // Epilogue first (pure reg/global — overlaps tail-DMA latency), drain after.
    // C/D layout col = lane&15, row = (lane>>4)*4 + reg (m89-verified).
#pragma unroll
    for (int m = 0; m < 8; ++m) {
#pragma unroll
        for (int jj = 0; jj < 4; ++jj) {
            const int row = brow + wr * 128 + m * 16 + fq * 4 + jj;
            const float* xp = xdot + (size_t)row * DTOT + bcol + wc * 64 + fr;
            float pns = 0.f, psx = 0.f, pxx = 0.f;
#pragma unroll
            for (int n = 0; n < 4; ++n) {
                float s  = acc[m][n][jj];
                float xv = xp[n * 16];
                pns += s * s; psx += s * xv; pxx += xv * xv;
            }
#pragma unroll
            for (int msk = 1; msk < 16; msk <<= 1) {
                pns += __shfl_xor(pns, msk);
                psx += __shfl_xor(psx, msk);
                pxx += __shfl_xor(pxx, msk);
            }
            if (fr == 0) {
                atomicAdd(&ns_acc[row], pns);
                atomicAdd(&sx_acc[row], psx);
                atomicAdd(&xx_acc[row], pxx);
            }
        }
    }
    WAITV(0);   // drain clamped tail B-DMA before LDS dealloc at exit
#undef FRAG
}

__global__ void finalize_k(const float* __restrict__ ns, const float* __restrict__ sx,
                           const float* __restrict__ xx, float* __restrict__ out) {
    int i = blockIdx.x * blockDim.x + threadIdx.x;
    if (i < MTOT) out[i] = xx[i] - (sx[i] * sx[i]) / (1.0f + ns[i]);
}

extern "C" void kernel_launch(void* const* d_in, const int* in_sizes, int n_in,
                              void* d_out, int out_size, void* d_ws, size_t ws_size,
                              hipStream_t stream) {
    const float* x  = (const float*)d_in[0];
    const float* xd = (const float*)d_in[1];
    const float* W  = (const float*)d_in[2];
    float* out = (float*)d_out;

    const size_t wbf_bytes = (size_t)DTOT * DTOT * 2;   //  8.4 MB
    const size_t acc_bytes = (size_t)3 * MTOT * 4;      //  0.2 MB

    u16* wbf = (u16*)d_ws;
    float* accs = (float*)((char*)d_ws + wbf_bytes);
    float* nsA = accs;
    float* sxA = accs + MTOT;
    float* xxA = accs + 2 * MTOT;
    (void)ws_size; (void)in_sizes; (void)n_in; (void)out_size;

    hipMemsetAsync(accs, 0, acc_bytes, stream);  // re-zero every call

    cast_kernel<<<1024, 256, 0, stream>>>(W, wbf, DTOT * DTOT / 8);
    gemm8<<<512, 512, 0, stream>>>(x, wbf, xd, nsA, sxA, xxA);
    finalize_k<<<MTOT / 256, 256, 0, stream>>>(nsA, sxA, xxA, out);
}

// Round 9
// 162.319 us; speedup vs baseline: 1.5009x; 1.5009x over previous
//
#include <hip/hip_runtime.h>

// out[b] = ||xd_b||^2 - (s_b . xd_b)^2 / (1 + ||s_b||^2), s = x @ W^T.
// R9: MX-fp8 (e4m3) MFMA GEMM on the m97-simple 128^2 structure (learn_hip
// m148 measured 1628 TF for exactly this port). W pre-scaled x64 into e4m3's
// normal range; s_mfma = 64 s  =>  out = xx - sx_m^2/(4096 + ns_m).
// mfma_scale_f32_16x16x128_f8f6f4 with scales = 0x7f7f7f7f (e8m0 1.0 in every
// byte -- invariant to scale byte/lane mapping). A/B fragment addressing is
// IDENTICAL for both operands, so any within-lane k-order misunderstanding
// cancels in the dot product. C/D layout is shape-determined (m127, incl.
// scaled f8f6f4) -> same verified epilogue as R1-R7.
// Numerics: absmax 8.0 in R1-R8 is a bf16-ULP artifact (out~2048, ULP=8.0);
// true GEMM-sourced error at fp8 is ~0.5 << threshold 46.4.

#define MTOT 16384
#define DTOT 2048
#define NK 16   // K-tiles of 128

typedef unsigned char u8;
typedef __attribute__((ext_vector_type(4))) float f32x4;
typedef __attribute__((ext_vector_type(8))) int i32x8;

// f32 -> OCP e4m3fn, RNE, saturating. Subnormal step 2^-9.
__device__ __forceinline__ u8 f2e4m3(float f) {
    union { float f; unsigned u; } v; v.f = f;
    unsigned u = v.u;
    unsigned sgn = (u >> 24) & 0x80;
    float ax = fabsf(f);
    if (ax < 0.015625f) {                       // < 2^-6: subnormal
        int m = (int)(ax * 512.0f + 0.5f);      // 0..8
        if (m == 8) return (u8)(sgn | 0x08);    // rounds up to 2^-6
        return (u8)(sgn | m);
    }
    u &= 0x7fffffff;
    u += 0x7ffff + ((u >> 20) & 1);             // RNE, keep 3 mantissa bits
    int E = (int)((u >> 23) & 0xff) - 127 + 7;  // e4m3 biased exponent
    if (E > 15) return (u8)(sgn | 0x7e);        // saturate to 448
    return (u8)(sgn | (E << 3) | ((u >> 20) & 7));
}

__device__ __forceinline__ void gload_lds16(const void* gptr, void* ldsptr) {
    __builtin_amdgcn_global_load_lds(
        (const __attribute__((address_space(1))) unsigned int*)gptr,
        (__attribute__((address_space(3))) unsigned int*)ldsptr,
        16, 0, 0);
}

#define BARS()   __builtin_amdgcn_s_barrier()
#define SCHED0() __builtin_amdgcn_sched_barrier(0)
#define LGKM0()  asm volatile("s_waitcnt lgkmcnt(0)")
#define WAITV0() asm volatile("s_waitcnt vmcnt(0)")

// ---------------- cast f32 -> e4m3 (16 elems/thread/iter) ----------------
__global__ void cast8_kernel(const float* __restrict__ src, u8* __restrict__ dst,
                             int n16, float mul) {
    int stride = gridDim.x * blockDim.x;
    for (int i = blockIdx.x * blockDim.x + threadIdx.x; i < n16; i += stride) {
        const f32x4* p = (const f32x4*)src + (size_t)i * 4;
        f32x4 a0 = p[0], a1 = p[1], a2 = p[2], a3 = p[3];
        uint4 r;
        r.x = (unsigned)f2e4m3(a0[0] * mul) | ((unsigned)f2e4m3(a0[1] * mul) << 8) |
              ((unsigned)f2e4m3(a0[2] * mul) << 16) | ((unsigned)f2e4m3(a0[3] * mul) << 24);
        r.y = (unsigned)f2e4m3(a1[0] * mul) | ((unsigned)f2e4m3(a1[1] * mul) << 8) |
              ((unsigned)f2e4m3(a1[2] * mul) << 16) | ((unsigned)f2e4m3(a1[3] * mul) << 24);
        r.z = (unsigned)f2e4m3(a2[0] * mul) | ((unsigned)f2e4m3(a2[1] * mul) << 8) |
              ((unsigned)f2e4m3(a2[2] * mul) << 16) | ((unsigned)f2e4m3(a2[3] * mul) << 24);
        r.w = (unsigned)f2e4m3(a3[0] * mul) | ((unsigned)f2e4m3(a3[1] * mul) << 8) |
              ((unsigned)f2e4m3(a3[2] * mul) << 16) | ((unsigned)f2e4m3(a3[3] * mul) << 24);
        ((uint4*)dst)[i] = r;
    }
}

// ---------------- fp8 128^2 GEMM (m97-simple) + fused reductions ----------------
// grid = 2048 blocks x 256 threads (4 waves, 2x2). Per wave 64x64 out =
// acc[4][4] of 16x16 frags; ONE mfma_scale 16x16x128 per frag per K-tile.
// LDS 32 KiB single-buffer: A [128 rows][128 B e4m3] + B at +16384.
// XCD k (= bid%8) owns W col panels {2k,2k+1} (0.5 MB, L2-resident).
// K-loop: {stage 8 gload16; vmcnt(0); bar; 16 frag-pair reads + 16 MFMA;
// lgkm(0); bar}. 3 blocks/CU provide the cross-block overlap (m97/m114).
__global__ __launch_bounds__(256, 3)
void gemmf8(const u8* __restrict__ xq, const u8* __restrict__ wq,
            const float* __restrict__ xdot,
            float* __restrict__ ns_acc, float* __restrict__ sx_acc,
            float* __restrict__ xx_acc) {
    __shared__ u8 lds[32768];

    const int tid  = threadIdx.x;
    const int lane = tid & 63;
    const int wid  = tid >> 6;
    const int wr = wid >> 1, wc = wid & 1;   // 2x2 wave grid
    const int fr = lane & 15, fq = lane >> 4;

    const int bid = blockIdx.x;              // 2048
    const int o   = (bid & 7) * 256 + (bid >> 3);
    const int brow = (o & 127) * 128;
    const int bcol = (o >> 7) * 128;

    // staging: 4 chunks each of A and B per thread; chunk c: row c>>3, 16B
    // slot c&7. Swizzle via pre-swizzled global source; LDS dest linear.
    const u8* xbase = xq + (size_t)brow * DTOT;
    const u8* wbase = wq + (size_t)bcol * DTOT;

    // swizzled fragment read: 32 B/lane as two b128 at slots (2fq, 2fq+1)^(row&7)
    auto rd8 = [&](int region, int row) -> i32x8 {
        const char* p = (const char*)lds + region + row * 128;
        int4 lo = *(const int4*)(p + (((2 * fq)     ^ (row & 7)) << 4));
        int4 hi = *(const int4*)(p + (((2 * fq + 1) ^ (row & 7)) << 4));
        i32x8 r;
        r[0] = lo.x; r[1] = lo.y; r[2] = lo.z; r[3] = lo.w;
        r[4] = hi.x; r[5] = hi.y; r[6] = hi.z; r[7] = hi.w;
        return r;
    };

    f32x4 acc[4][4] = {};
    i32x8 af[4], bf[4];

    for (int kt = 0; kt < NK; ++kt) {
        const int kb = kt * 128;   // byte offset along rows (fp8: 1 B/elem)
#pragma unroll
        for (int q = 0; q < 4; ++q) {
            const int c = tid + q * 256;
            const int row = c >> 3, slot = c & 7;
            const size_t go = (size_t)row * DTOT + kb + (((slot ^ (row & 7)) << 4));
            gload_lds16(xbase + go, (char*)lds + c * 16);
            gload_lds16(wbase + go, (char*)lds + 16384 + c * 16);
        }
        WAITV0();
        SCHED0(); BARS();

#pragma unroll
        for (int m = 0; m < 4; ++m) af[m] = rd8(0,     wr * 64 + m * 16 + fr);
#pragma unroll
        for (int n = 0; n < 4; ++n) bf[n] = rd8(16384, wc * 64 + n * 16 + fr);
#pragma unroll
        for (int m = 0; m < 4; ++m)
#pragma unroll
            for (int n = 0; n < 4; ++n)
                acc[m][n] = __builtin_amdgcn_mfma_scale_f32_16x16x128_f8f6f4(
                    af[m], bf[n], acc[m][n],
                    0, 0,                    // cbsz = e4m3 (A), blgp = e4m3 (B)
                    0, 0x7f7f7f7f,           // scale A: sel 0, e8m0 1.0 all bytes
                    0, 0x7f7f7f7f);          // scale B
        LGKM0();
        SCHED0(); BARS();
    }

    // Epilogue: C/D col = lane&15, row = (lane>>4)*4 + reg (shape-determined,
    // m89/m127). Reduce s^2, s*xd, xd^2 over fr; 1 atomicAdd/row/qty/wave.
#pragma unroll
    for (int m = 0; m < 4; ++m) {
#pragma unroll
        for (int jj = 0; jj < 4; ++jj) {
            const int row = brow + wr * 64 + m * 16 + fq * 4 + jj;
            const float* xp = xdot + (size_t)row * DTOT + bcol + wc * 64 + fr;
            float pns = 0.f, psx = 0.f, pxx = 0.f;
#pragma unroll
            for (int n = 0; n < 4; ++n) {
                float s  = acc[m][n][jj];   // = 64 * s_true
                float xv = xp[n * 16];
                pns += s * s; psx += s * xv; pxx += xv * xv;
            }
#pragma unroll
            for (int msk = 1; msk < 16; msk <<= 1) {
                pns += __shfl_xor(pns, msk);
                psx += __shfl_xor(psx, msk);
                pxx += __shfl_xor(pxx, msk);
            }
            if (fr == 0) {
                atomicAdd(&ns_acc[row], pns);
                atomicAdd(&sx_acc[row], psx);
                atomicAdd(&xx_acc[row], pxx);
            }
        }
    }
}

__global__ void finalize_k(const float* __restrict__ ns, const float* __restrict__ sx,
                           const float* __restrict__ xx, float* __restrict__ out) {
    int i = blockIdx.x * blockDim.x + threadIdx.x;
    // ns,sx carry the x64 W-prescale: sx_true^2/(1+ns_true) = sx^2/(4096+ns)
    if (i < MTOT) out[i] = xx[i] - (sx[i] * sx[i]) / (4096.0f + ns[i]);
}

extern "C" void kernel_launch(void* const* d_in, const int* in_sizes, int n_in,
                              void* d_out, int out_size, void* d_ws, size_t ws_size,
                              hipStream_t stream) {
    const float* x  = (const float*)d_in[0];
    const float* xd = (const float*)d_in[1];
    const float* W  = (const float*)d_in[2];
    float* out = (float*)d_out;

    const size_t xq_bytes = (size_t)MTOT * DTOT;   // 33.6 MB
    const size_t wq_bytes = (size_t)DTOT * DTOT;   //  4.2 MB
    const size_t acc_bytes = (size_t)3 * MTOT * 4; //  0.2 MB

    u8* xq = (u8*)d_ws;
    u8* wq = (u8*)((char*)d_ws + xq_bytes);
    float* accs = (float*)((char*)d_ws + xq_bytes + wq_bytes);
    float* nsA = accs;
    float* sxA = accs + MTOT;
    float* xxA = accs + 2 * MTOT;
    (void)ws_size; (void)in_sizes; (void)n_in; (void)out_size;

    hipMemsetAsync(accs, 0, acc_bytes, stream);  // re-zero every call

    cast8_kernel<<<2048, 256, 0, stream>>>(x, xq, MTOT * DTOT / 16, 1.0f);
    cast8_kernel<<<512, 256, 0, stream>>>(W, wq, DTOT * DTOT / 16, 64.0f);
    gemmf8<<<2048, 256, 0, stream>>>(xq, wq, xd, nsA, sxA, xxA);
    finalize_k<<<MTOT / 256, 256, 0, stream>>>(nsA, sxA, xxA, out);
}

// Round 10
// 156.910 us; speedup vs baseline: 1.5527x; 1.0345x over previous
//
#include <hip/hip_runtime.h>

// out[b] = ||xd_b||^2 - (s_b . xd_b)^2 / (1 + ||s_b||^2), s = x @ W^T.
// R10: MX-fp8 (e4m3) GEMM, 256x256 tile, BK=128, 8 waves (2Mx4N), per-wave
// 128x64 = acc[8][4], ONE mfma_scale_16x16x128 per frag (scales=1.0).
// Fixes vs R9 (127us, 22% MfmaUtil, 8.4M bank conflicts):
//  (a) conflict fix: LDS slot PERMUTATION so frag reads use the exact slot
//      sets proven conflict-free in bf16 R2-R7: logical slot q holds global
//      16B-unit u = (q<4 ? 2q : 2q-7); lane reads lo at q=fq, hi at q=4+fq,
//      physical = q ^ (row&7). R9's paired-slot (2fq,2fq+1) pattern is gone.
//  (b) volume fix: 128x64 per wave (vs 64x64) halves LDS bytes/FLOP; per
//      CU-kt MFMA 2213 cyc vs LDS ~1700 -> compute-bound.
// K-loop = catalog minimum-2-phase: STAGE(t+1)->other buf, read+MFMA cur,
// lgkm(0), vmcnt(0), barrier. W pre-scaled x64 -> finalize /(4096+ns).

#define MTOT 16384
#define DTOT 2048
#define NK 16   // K-tiles of 128

typedef unsigned char u8;
typedef __attribute__((ext_vector_type(4))) float f32x4;
typedef __attribute__((ext_vector_type(8))) int i32x8;

// f32 -> OCP e4m3fn, RNE, saturating. Subnormal step 2^-9.
__device__ __forceinline__ u8 f2e4m3(float f) {
    union { float f; unsigned u; } v; v.f = f;
    unsigned u = v.u;
    unsigned sgn = (u >> 24) & 0x80;
    float ax = fabsf(f);
    if (ax < 0.015625f) {                       // < 2^-6: subnormal
        int m = (int)(ax * 512.0f + 0.5f);      // 0..8
        if (m == 8) return (u8)(sgn | 0x08);
        return (u8)(sgn | m);
    }
    u &= 0x7fffffff;
    u += 0x7ffff + ((u >> 20) & 1);             // RNE, keep 3 mantissa bits
    int E = (int)((u >> 23) & 0xff) - 127 + 7;
    if (E > 15) return (u8)(sgn | 0x7e);        // saturate to 448
    return (u8)(sgn | (E << 3) | ((u >> 20) & 7));
}

__device__ __forceinline__ void gload_lds16(const void* gptr, void* ldsptr) {
    __builtin_amdgcn_global_load_lds(
        (const __attribute__((address_space(1))) unsigned int*)gptr,
        (__attribute__((address_space(3))) unsigned int*)ldsptr,
        16, 0, 0);
}

#define BARS()   __builtin_amdgcn_s_barrier()
#define SCHED0() __builtin_amdgcn_sched_barrier(0)
#define LGKM0()  asm volatile("s_waitcnt lgkmcnt(0)")
#define WAITV0() asm volatile("s_waitcnt vmcnt(0)")

// ---------------- cast f32 -> e4m3 (16 elems/thread/iter) ----------------
__global__ void cast8_kernel(const float* __restrict__ src, u8* __restrict__ dst,
                             int n16, float mul) {
    int stride = gridDim.x * blockDim.x;
    for (int i = blockIdx.x * blockDim.x + threadIdx.x; i < n16; i += stride) {
        const f32x4* p = (const f32x4*)src + (size_t)i * 4;
        f32x4 a0 = p[0], a1 = p[1], a2 = p[2], a3 = p[3];
        uint4 r;
        r.x = (unsigned)f2e4m3(a0[0] * mul) | ((unsigned)f2e4m3(a0[1] * mul) << 8) |
              ((unsigned)f2e4m3(a0[2] * mul) << 16) | ((unsigned)f2e4m3(a0[3] * mul) << 24);
        r.y = (unsigned)f2e4m3(a1[0] * mul) | ((unsigned)f2e4m3(a1[1] * mul) << 8) |
              ((unsigned)f2e4m3(a1[2] * mul) << 16) | ((unsigned)f2e4m3(a1[3] * mul) << 24);
        r.z = (unsigned)f2e4m3(a2[0] * mul) | ((unsigned)f2e4m3(a2[1] * mul) << 8) |
              ((unsigned)f2e4m3(a2[2] * mul) << 16) | ((unsigned)f2e4m3(a2[3] * mul) << 24);
        r.w = (unsigned)f2e4m3(a3[0] * mul) | ((unsigned)f2e4m3(a3[1] * mul) << 8) |
              ((unsigned)f2e4m3(a3[2] * mul) << 16) | ((unsigned)f2e4m3(a3[3] * mul) << 24);
        ((uint4*)dst)[i] = r;
    }
}

// ---------------- fp8 256^2 GEMM + fused reductions ----------------
// grid = 512 blocks x 512 threads. LDS 128 KiB: [2 buf][A0,A1,B0,B1 x 16 KiB],
// each region [128 rows][128 B]. XCD k (= bid%8) owns W col panel k*256.
__global__ __launch_bounds__(512, 2)
void gemmf8(const u8* __restrict__ xq, const u8* __restrict__ wq,
            const float* __restrict__ xdot,
            float* __restrict__ ns_acc, float* __restrict__ sx_acc,
            float* __restrict__ xx_acc) {
    __shared__ u8 lds[131072];

    const int tid  = threadIdx.x;
    const int lane = tid & 63;
    const int wid  = tid >> 6;
    const int wr = wid >> 2, wc = wid & 3;   // 2 x 4 wave grid
    const int fr = lane & 15, fq = lane >> 4;

    const int bid  = blockIdx.x;             // 512
    const int brow = (bid >> 3) * 256;
    const int bcol = (bid & 7) * 256;

    // ---- staging: one 128-row half-tile (16 KiB) = 2 chunks/thread.
    // chunk c: row c>>3, physical slot p = c&7; logical q = p^(row&7);
    // global unit u = (q<4 ? 2q : 2q-7). LDS dest linear (DMA constraint).
    auto stage_half = [&](const u8* src, int region) {
#pragma unroll
        for (int c2 = 0; c2 < 2; ++c2) {
            const int c = c2 * 512 + tid;
            const int row = c >> 3, p = c & 7;
            const int q = p ^ (row & 7);
            const int u = q < 4 ? 2 * q : 2 * q - 7;
            gload_lds16(src + (size_t)row * DTOT + u * 16,
                        (char*)lds + region + c * 16);
        }
    };
    auto stage_tile = [&](int kt, int bufbyte) {
        const int kb = kt * 128;
        stage_half(xq + (size_t)(brow)       * DTOT + kb, bufbyte);
        stage_half(xq + (size_t)(brow + 128) * DTOT + kb, bufbyte + 16384);
        stage_half(wq + (size_t)(bcol)       * DTOT + kb, bufbyte + 32768);
        stage_half(wq + (size_t)(bcol + 128) * DTOT + kb, bufbyte + 49152);
    };

    // frag read: lane wants global units 2fq (lo), 2fq+1 (hi) of its row
    // -> logical slots q=fq and q=4+fq, physical = q^(row&7). These are the
    // exact slot sets the bf16 FRAG used (0 conflicts, R2-R7).
    auto rdfrag = [&](int region, int row) -> i32x8 {
        const char* pr = (const char*)lds + region + row * 128;
        int4 lo = *(const int4*)(pr + ((fq       ^ (row & 7)) << 4));
        int4 hi = *(const int4*)(pr + (((4 + fq) ^ (row & 7)) << 4));
        i32x8 r;
        r[0] = lo.x; r[1] = lo.y; r[2] = lo.z; r[3] = lo.w;
        r[4] = hi.x; r[5] = hi.y; r[6] = hi.z; r[7] = hi.w;
        return r;
    };

    f32x4 acc[8][4] = {};
    i32x8 bf[4], a0, a1;

    // ---- prologue
    stage_tile(0, 0);
    WAITV0();
    SCHED0(); BARS();

    for (int t = 0; t < NK; ++t) {
        const int buf   = (t & 1) * 65536;
        const int abase = buf + wr * 16384;                    // A half = wr
        const int bbase = buf + 32768 + (wc >> 1) * 16384;     // B half = wc>>1
        const int brB   = (wc & 1) * 64;

        if (t + 1 < NK) stage_tile(t + 1, (~t & 1) * 65536);

#pragma unroll
        for (int n = 0; n < 4; ++n) bf[n] = rdfrag(bbase, brB + n * 16 + fr);
        a0 = rdfrag(abase, fr);   // m=0
#pragma unroll
        for (int m = 0; m < 8; ++m) {
            if (m + 1 < 8) a1 = rdfrag(abase, (m + 1) * 16 + fr);
            __builtin_amdgcn_s_setprio(1);
#pragma unroll
            for (int n = 0; n < 4; ++n)
                acc[m][n] = __builtin_amdgcn_mfma_scale_f32_16x16x128_f8f6f4(
                    a0, bf[n], acc[m][n],
                    0, 0,                    // A,B fmt = e4m3
                    0, 0x7f7f7f7f,           // scale A = 1.0
                    0, 0x7f7f7f7f);          // scale B = 1.0
            __builtin_amdgcn_s_setprio(0);
            a0 = a1;
        }
        LGKM0();    // cur-buf reads drained (WAR vs t+2's stage, via next bar)
        WAITV0();   // next tile's DMA landed
        SCHED0(); BARS();
    }

    // Epilogue: C/D col = lane&15, row = (lane>>4)*4 + reg (shape-determined).
    // Reduce s^2, s*xd, xd^2 over fr; 1 atomicAdd/row/qty/wave.
#pragma unroll
    for (int m = 0; m < 8; ++m) {
#pragma unroll
        for (int jj = 0; jj < 4; ++jj) {
            const int row = brow + wr * 128 + m * 16 + fq * 4 + jj;
            const float* xp = xdot + (size_t)row * DTOT + bcol + wc * 64 + fr;
            float pns = 0.f, psx = 0.f, pxx = 0.f;
#pragma unroll
            for (int n = 0; n < 4; ++n) {
                float s  = acc[m][n][jj];   // = 64 * s_true
                float xv = xp[n * 16];
                pns += s * s; psx += s * xv; pxx += xv * xv;
            }
#pragma unroll
            for (int msk = 1; msk < 16; msk <<= 1) {
                pns += __shfl_xor(pns, msk);
                psx += __shfl_xor(psx, msk);
                pxx += __shfl_xor(pxx, msk);
            }
            if (fr == 0) {
                atomicAdd(&ns_acc[row], pns);
                atomicAdd(&sx_acc[row], psx);
                atomicAdd(&xx_acc[row], pxx);
            }
        }
    }
}

__global__ void finalize_k(const float* __restrict__ ns, const float* __restrict__ sx,
                           const float* __restrict__ xx, float* __restrict__ out) {
    int i = blockIdx.x * blockDim.x + threadIdx.x;
    // ns,sx carry the x64 W-prescale: sx_true^2/(1+ns_true) = sx^2/(4096+ns)
    if (i < MTOT) out[i] = xx[i] - (sx[i] * sx[i]) / (4096.0f + ns[i]);
}

extern "C" void kernel_launch(void* const* d_in, const int* in_sizes, int n_in,
                              void* d_out, int out_size, void* d_ws, size_t ws_size,
                              hipStream_t stream) {
    const float* x  = (const float*)d_in[0];
    const float* xd = (const float*)d_in[1];
    const float* W  = (const float*)d_in[2];
    float* out = (float*)d_out;

    const size_t xq_bytes = (size_t)MTOT * DTOT;   // 33.6 MB
    const size_t wq_bytes = (size_t)DTOT * DTOT;   //  4.2 MB
    const size_t acc_bytes = (size_t)3 * MTOT * 4; //  0.2 MB

    u8* xq = (u8*)d_ws;
    u8* wq = (u8*)((char*)d_ws + xq_bytes);
    float* accs = (float*)((char*)d_ws + xq_bytes + wq_bytes);
    float* nsA = accs;
    float* sxA = accs + MTOT;
    float* xxA = accs + 2 * MTOT;
    (void)ws_size; (void)in_sizes; (void)n_in; (void)out_size;

    hipMemsetAsync(accs, 0, acc_bytes, stream);  // re-zero every call

    cast8_kernel<<<2048, 256, 0, stream>>>(x, xq, MTOT * DTOT / 16, 1.0f);
    cast8_kernel<<<512, 256, 0, stream>>>(W, wq, DTOT * DTOT / 16, 64.0f);
    gemmf8<<<512, 512, 0, stream>>>(xq, wq, xd, nsA, sxA, xxA);
    finalize_k<<<MTOT / 256, 256, 0, stream>>>(nsA, sxA, xxA, out);
}